// Round 3
// baseline (2592.076 us; speedup 1.0000x reference)
//
#include <hip/hip_runtime.h>
#include <math.h>

#define Bq 32
#define Sq 32
#define Nn 32
#define Eg 128
#define Hh 4
#define Dd 300
#define Ff 150
#define Uu 1024
#define DINq 900
#define Vv 50000
#define Gq (Bq * Sq)

typedef __bf16 bf16x8 __attribute__((ext_vector_type(8)));
typedef __bf16 bf16x4 __attribute__((ext_vector_type(4)));
typedef float f32x4 __attribute__((ext_vector_type(4)));

// ---------------------------------------------------------------------------
// wa[h,d] = sum_f W_gat[h,d,f] * a[h,f]
// ---------------------------------------------------------------------------
__global__ __launch_bounds__(256) void compute_wa_kernel(
    const float* __restrict__ W_gat, const float* __restrict__ a_src,
    const float* __restrict__ a_dst, float* __restrict__ wa_src,
    float* __restrict__ wa_dst) {
  int idx = blockIdx.x * 256 + threadIdx.x;
  if (idx >= 2 * Hh * Dd) return;
  int which = idx / (Hh * Dd);
  int hd = idx - which * (Hh * Dd);
  int h = hd / Dd;
  const float* a = (which ? a_dst : a_src) + h * Ff;
  const float* w = W_gat + (size_t)hd * Ff;
  float acc = 0.f;
  for (int f = 0; f < Ff; ++f) acc = fmaf(w[f], a[f], acc);
  (which ? wa_dst : wa_src)[hd] = acc;
}

// ---------------------------------------------------------------------------
// GAT reduced to dst==0 edges (+ self-loop); writes xs row (s*B+b) =
// [X[node0] (300) | gat_out (600)]  (time-major GRU input)
// ---------------------------------------------------------------------------
__global__ __launch_bounds__(256) void gat_kernel(
    const int* __restrict__ xidx, const int* __restrict__ eidx,
    const float* __restrict__ X, const float* __restrict__ W_gat,
    const float* __restrict__ b_gat, const float* __restrict__ wa_src,
    const float* __restrict__ wa_dst, float* __restrict__ xs) {
  int g = blockIdx.x;
  int b = g / Sq, s = g - b * Sq;
  int tid = threadIdx.x;
  __shared__ int cnt_s;
  __shared__ int src_l[Eg + 1];
  __shared__ int gnode[Eg + 1];
  __shared__ float al_d0[Hh];
  __shared__ float sc[Eg + 1][Hh];
  __shared__ float xbar[Hh][Dd];

  const int* eg_src = eidx + (size_t)g * 2 * Eg;
  const int* eg_dst = eg_src + Eg;
  if (tid == 0) { cnt_s = 1; src_l[0] = 0; }  // self-loop (0,0)
  __syncthreads();
  if (tid < Eg) {
    if (eg_dst[tid] == 0) {
      int p = atomicAdd(&cnt_s, 1);
      src_l[p] = eg_src[tid];
    }
  }
  __syncthreads();
  int cnt = cnt_s;
  int node0 = xidx[(size_t)g * Nn];
  for (int i = tid; i < cnt; i += 256) gnode[i] = xidx[(size_t)g * Nn + src_l[i]];

  {
    int h = tid >> 6, lane = tid & 63;
    const float* xrow = X + (size_t)node0 * Dd;
    const float* wd = wa_dst + h * Dd;
    float p = 0.f;
    for (int d = lane; d < Dd; d += 64) p = fmaf(xrow[d], wd[d], p);
    for (int off = 32; off; off >>= 1) p += __shfl_down(p, off);
    if (lane == 0) al_d0[h] = p;
  }
  __syncthreads();
  {
    int wave = tid >> 6, lane = tid & 63;
    for (int q = wave; q < cnt * Hh; q += 4) {
      int i = q >> 2, h = q & 3;
      const float* xrow = X + (size_t)gnode[i] * Dd;
      const float* wsrc = wa_src + h * Dd;
      float p = 0.f;
      for (int d = lane; d < Dd; d += 64) p = fmaf(xrow[d], wsrc[d], p);
      for (int off = 32; off; off >>= 1) p += __shfl_down(p, off);
      if (lane == 0) {
        float v = p + al_d0[h];
        sc[i][h] = v > 0.f ? v : 0.2f * v;
      }
    }
  }
  __syncthreads();
  {
    int h = tid >> 6, lane = tid & 63;
    float m = -1e30f;
    for (int i = lane; i < cnt; i += 64) m = fmaxf(m, sc[i][h]);
    for (int off = 32; off; off >>= 1) m = fmaxf(m, __shfl_down(m, off));
    m = __shfl(m, 0);
    float ssum = 0.f;
    for (int i = lane; i < cnt; i += 64) {
      float e = expf(sc[i][h] - m);
      sc[i][h] = e;
      ssum += e;
    }
    for (int off = 32; off; off >>= 1) ssum += __shfl_down(ssum, off);
    ssum = __shfl(ssum, 0);
    float inv = 1.f / ssum;
    for (int i = lane; i < cnt; i += 64) sc[i][h] *= inv;
  }
  __syncthreads();
  for (int p = tid; p < Hh * Dd; p += 256) {
    int h = p / Dd, d = p - h * Dd;
    float a = 0.f;
    for (int i = 0; i < cnt; ++i) a = fmaf(sc[i][h], X[(size_t)gnode[i] * Dd + d], a);
    xbar[h][d] = a;
  }
  __syncthreads();
  float* row = xs + (size_t)(s * Bq + b) * DINq;
  {
    const float* x0 = X + (size_t)node0 * Dd;
    for (int d = tid; d < Dd; d += 256) row[d] = x0[d];
  }
  for (int p = tid; p < Hh * Ff; p += 256) {
    int h = p / Ff, f = p - h * Ff;
    const float* wg = W_gat + (size_t)h * Dd * Ff + f;
    float a = b_gat[p];
    for (int d = 0; d < Dd; ++d) a = fmaf(xbar[h][d], wg[(size_t)d * Ff], a);
    row[Dd + p] = a;
  }
}

// ---------------------------------------------------------------------------
// fp32 GEMM (kept for gi GEMMs + fallback): C = bias + A @ Bt^T
// ---------------------------------------------------------------------------
template <int BM, int BN, int MH, int NH>
__global__ __launch_bounds__(256) void gemm_bias_kernel(
    const float* __restrict__ A, const float* __restrict__ Bt,
    const float* __restrict__ bias, float* __restrict__ C,
    int M, int N, int K) {
  constexpr int BK = 16;
  __shared__ __align__(16) float As[BK][BM];
  __shared__ __align__(16) float Bs[BK][BN];
  int tid = threadIdx.x;
  int tx = tid & 15, ty = tid >> 4;
  int m0 = blockIdx.y * BM, n0 = blockIdx.x * BN;
  float acc[MH][NH][4][4];
#pragma unroll
  for (int a = 0; a < MH; ++a)
#pragma unroll
    for (int bb = 0; bb < NH; ++bb)
#pragma unroll
      for (int i = 0; i < 4; ++i)
#pragma unroll
        for (int j = 0; j < 4; ++j) acc[a][bb][i][j] = 0.f;

  int sk = (tid & 3) * 4;
  int sr = tid >> 2;

  for (int k0 = 0; k0 < K; k0 += BK) {
    bool fullk = (k0 + BK <= K);
#pragma unroll
    for (int rr = 0; rr < BM; rr += 64) {
      int m = m0 + sr + rr;
      float4 v = {0.f, 0.f, 0.f, 0.f};
      if (m < M) {
        const float* ap = A + (size_t)m * K + k0 + sk;
        if (fullk || (K - (k0 + sk) >= 4)) {
          v = *(const float4*)ap;
        } else {
          int rem = K - (k0 + sk);
          if (rem > 0) v.x = ap[0];
          if (rem > 1) v.y = ap[1];
          if (rem > 2) v.z = ap[2];
        }
      }
      As[sk + 0][sr + rr] = v.x;
      As[sk + 1][sr + rr] = v.y;
      As[sk + 2][sr + rr] = v.z;
      As[sk + 3][sr + rr] = v.w;
    }
#pragma unroll
    for (int rr = 0; rr < BN; rr += 64) {
      int n = n0 + sr + rr;
      float4 v = {0.f, 0.f, 0.f, 0.f};
      if (n < N) {
        const float* bp = Bt + (size_t)n * K + k0 + sk;
        if (fullk || (K - (k0 + sk) >= 4)) {
          v = *(const float4*)bp;
        } else {
          int rem = K - (k0 + sk);
          if (rem > 0) v.x = bp[0];
          if (rem > 1) v.y = bp[1];
          if (rem > 2) v.z = bp[2];
        }
      }
      Bs[sk + 0][sr + rr] = v.x;
      Bs[sk + 1][sr + rr] = v.y;
      Bs[sk + 2][sr + rr] = v.z;
      Bs[sk + 3][sr + rr] = v.w;
    }
    __syncthreads();
#pragma unroll
    for (int kk = 0; kk < BK; ++kk) {
      float ar[MH][4], br[NH][4];
#pragma unroll
      for (int a = 0; a < MH; ++a) {
        float4 v = *(const float4*)&As[kk][ty * 4 + a * (BM / 2)];
        ar[a][0] = v.x; ar[a][1] = v.y; ar[a][2] = v.z; ar[a][3] = v.w;
      }
#pragma unroll
      for (int bb = 0; bb < NH; ++bb) {
        float4 v = *(const float4*)&Bs[kk][tx * 4 + bb * (BN / 2)];
        br[bb][0] = v.x; br[bb][1] = v.y; br[bb][2] = v.z; br[bb][3] = v.w;
      }
#pragma unroll
      for (int a = 0; a < MH; ++a)
#pragma unroll
        for (int bb = 0; bb < NH; ++bb)
#pragma unroll
          for (int i = 0; i < 4; ++i)
#pragma unroll
            for (int j = 0; j < 4; ++j)
              acc[a][bb][i][j] = fmaf(ar[a][i], br[bb][j], acc[a][bb][i][j]);
    }
    __syncthreads();
  }
#pragma unroll
  for (int a = 0; a < MH; ++a)
#pragma unroll
    for (int i = 0; i < 4; ++i) {
      int m = m0 + ty * 4 + a * (BM / 2) + i;
      if (m >= M) continue;
#pragma unroll
      for (int bb = 0; bb < NH; ++bb)
#pragma unroll
        for (int j = 0; j < 4; ++j) {
          int n = n0 + tx * 4 + bb * (BN / 2) + j;
          if (n < N) C[(size_t)m * N + n] = acc[a][bb][i][j] + bias[n];
        }
    }
}

// ---------------------------------------------------------------------------
// split x (fp32) -> hi = bf16(x), lo = bf16(x - hi).  3-term bf16 GEMM gives
// ~fp32 accuracy: dropped al*bl term is ~2^-16 relative.
// ---------------------------------------------------------------------------
__global__ __launch_bounds__(256) void split_bf16_kernel(
    const float* __restrict__ in, __bf16* __restrict__ hi,
    __bf16* __restrict__ lo, int n4) {
  int stride = gridDim.x * 256;
  for (int i = blockIdx.x * 256 + threadIdx.x; i < n4; i += stride) {
    float4 v = ((const float4*)in)[i];
    bf16x4 hv, lv;
    hv.x = (__bf16)v.x; lv.x = (__bf16)(v.x - (float)hv.x);
    hv.y = (__bf16)v.y; lv.y = (__bf16)(v.y - (float)hv.y);
    hv.z = (__bf16)v.z; lv.z = (__bf16)(v.z - (float)hv.z);
    hv.w = (__bf16)v.w; lv.w = (__bf16)(v.w - (float)hv.w);
    ((bf16x4*)hi)[i] = hv;
    ((bf16x4*)lo)[i] = lv;
  }
}

// async 16B global -> LDS (dest = wave-uniform base + lane*16)
__device__ __forceinline__ void glds16(const void* g, void* l) {
  __builtin_amdgcn_global_load_lds(
      (const __attribute__((address_space(1))) void*)g,
      (__attribute__((address_space(3))) void*)l, 16, 0, 0);
}

// ---------------------------------------------------------------------------
// logits = A @ B^T + bias via bf16x3 split MFMA.
// A: [1024, K=1024] (hi/lo bf16), B^T = W_out: [N=50000, K] (hi/lo bf16).
// Block tile 128x128, 4 waves (2x2), per-wave 64x64 = 4x4 frags of 16x16.
// LDS layout [kb][row][8k] -> ds_read_b128 conflict-free; staged with
// global_load_lds width 16 (lane's src row = LDS base row + lane).
// grid = (m-tiles=8, n-tiles=391): 8 consecutive blocks share one B slab (L2).
// ---------------------------------------------------------------------------
__global__ __launch_bounds__(256) void logits_mfma_kernel(
    const __bf16* __restrict__ Ahi, const __bf16* __restrict__ Alo,
    const __bf16* __restrict__ Bhi, const __bf16* __restrict__ Blo,
    const float* __restrict__ bias, float* __restrict__ C) {
  constexpr int M = 1024, N = Vv, K = Uu;
  __shared__ __align__(16) __bf16 Ah[4][128][8];
  __shared__ __align__(16) __bf16 Al[4][128][8];
  __shared__ __align__(16) __bf16 Bh[4][128][8];
  __shared__ __align__(16) __bf16 Bl[4][128][8];
  int tid = threadIdx.x;
  int lane = tid & 63, w = tid >> 6;
  int wrow = w >> 1, wcol = w & 1;
  int m0 = blockIdx.x * 128, n0 = blockIdx.y * 128;
  f32x4 acc[4][4] = {};

  for (int k0 = 0; k0 < K; k0 += 32) {
    // stage 32 KB: each wave issues 8 x 1KB global_load_lds
#pragma unroll
    for (int c = w; c < 8; c += 4) {
      int kb = c >> 1, half = (c & 1) * 64;
      int row = half + lane;
      size_t ka = (size_t)(m0 + row) * K + (k0 + kb * 8);
      int bn = n0 + row;
      if (bn > N - 1) bn = N - 1;  // tail n-tile: clamp src row, mask on write
      size_t kbo = (size_t)bn * K + (k0 + kb * 8);
      glds16(Ahi + ka, &Ah[kb][half][0]);
      glds16(Alo + ka, &Al[kb][half][0]);
      glds16(Bhi + kbo, &Bh[kb][half][0]);
      glds16(Blo + kbo, &Bl[kb][half][0]);
    }
    __syncthreads();  // drains vmcnt -> staged data visible
    {
      int lm = lane & 15, kb2 = lane >> 4;
      bf16x8 ah[4], al[4], bh[4], bl[4];
#pragma unroll
      for (int f = 0; f < 4; ++f) {
        ah[f] = *(const bf16x8*)&Ah[kb2][wrow * 64 + f * 16 + lm][0];
        al[f] = *(const bf16x8*)&Al[kb2][wrow * 64 + f * 16 + lm][0];
        bh[f] = *(const bf16x8*)&Bh[kb2][wcol * 64 + f * 16 + lm][0];
        bl[f] = *(const bf16x8*)&Bl[kb2][wcol * 64 + f * 16 + lm][0];
      }
#pragma unroll
      for (int fm = 0; fm < 4; ++fm)
#pragma unroll
        for (int fn = 0; fn < 4; ++fn) {
          acc[fm][fn] = __builtin_amdgcn_mfma_f32_16x16x32_bf16(
              ah[fm], bh[fn], acc[fm][fn], 0, 0, 0);
          acc[fm][fn] = __builtin_amdgcn_mfma_f32_16x16x32_bf16(
              ah[fm], bl[fn], acc[fm][fn], 0, 0, 0);
          acc[fm][fn] = __builtin_amdgcn_mfma_f32_16x16x32_bf16(
              al[fm], bh[fn], acc[fm][fn], 0, 0, 0);
        }
    }
    __syncthreads();  // all waves done reading before next overwrite
  }

  // C/D layout (HW-verified m89/m91): col = lane&15, row = (lane>>4)*4 + reg
  int lm = lane & 15, rg = lane >> 4;
#pragma unroll
  for (int fm = 0; fm < 4; ++fm) {
    int mrow = m0 + wrow * 64 + fm * 16 + rg * 4;
#pragma unroll
    for (int fn = 0; fn < 4; ++fn) {
      int ncol = n0 + wcol * 64 + fn * 16 + lm;
      if (ncol < N) {
        float bv = bias[ncol];
#pragma unroll
        for (int r = 0; r < 4; ++r)
          C[(size_t)(mrow + r) * N + ncol] = acc[fm][fn][r] + bv;
      }
    }
  }
}

// ---------------------------------------------------------------------------
// One GRU scan step. h stored transposed [U][B].
// ---------------------------------------------------------------------------
__global__ __launch_bounds__(256) void gru_step_kernel(
    const float* __restrict__ gi_s, const float* __restrict__ w_hh,
    const float* __restrict__ b_hh, const float* __restrict__ h_in,
    float* __restrict__ h_out, float* __restrict__ ys_out) {
  int tid = threadIdx.x;
  int b = tid & 31, ui = (tid >> 5) & 1, kq = tid >> 6;
  int u = (blockIdx.x << 1) + ui;
  const float4* wr4 = (const float4*)(w_hh + (size_t)u * Uu + kq * 256);
  const float4* wz4 = (const float4*)(w_hh + ((size_t)Uu + u) * Uu + kq * 256);
  const float4* wn4 = (const float4*)(w_hh + ((size_t)2 * Uu + u) * Uu + kq * 256);
  const float* hp = h_in + (size_t)kq * 256 * Bq + b;
  float ar = 0.f, az = 0.f, an = 0.f;
#pragma unroll 8
  for (int kv = 0; kv < 64; ++kv) {
    float4 wr = wr4[kv], wz = wz4[kv], wn = wn4[kv];
    float h0 = hp[(kv * 4 + 0) * Bq];
    float h1 = hp[(kv * 4 + 1) * Bq];
    float h2 = hp[(kv * 4 + 2) * Bq];
    float h3 = hp[(kv * 4 + 3) * Bq];
    ar = fmaf(h0, wr.x, ar); ar = fmaf(h1, wr.y, ar);
    ar = fmaf(h2, wr.z, ar); ar = fmaf(h3, wr.w, ar);
    az = fmaf(h0, wz.x, az); az = fmaf(h1, wz.y, az);
    az = fmaf(h2, wz.z, az); az = fmaf(h3, wz.w, az);
    an = fmaf(h0, wn.x, an); an = fmaf(h1, wn.y, an);
    an = fmaf(h2, wn.z, an); an = fmaf(h3, wn.w, an);
  }
  __shared__ float red[3][4][64];
  int p = tid & 63;
  red[0][kq][p] = ar;
  red[1][kq][p] = az;
  red[2][kq][p] = an;
  __syncthreads();
  if (tid < 64) {
    int bb = tid & 31, uu = (tid >> 5) & 1;
    int uo = (blockIdx.x << 1) + uu;
    float gr = red[0][0][tid] + red[0][1][tid] + red[0][2][tid] + red[0][3][tid] + b_hh[uo];
    float gz = red[1][0][tid] + red[1][1][tid] + red[1][2][tid] + red[1][3][tid] + b_hh[Uu + uo];
    float gn = red[2][0][tid] + red[2][1][tid] + red[2][2][tid] + red[2][3][tid] + b_hh[2 * Uu + uo];
    const float* gip = gi_s + (size_t)bb * (3 * Uu);
    float r = 1.f / (1.f + expf(-(gip[uo] + gr)));
    float z = 1.f / (1.f + expf(-(gip[Uu + uo] + gz)));
    float n = tanhf(gip[2 * Uu + uo] + r * gn);
    float hprev = h_in[(size_t)uo * Bq + bb];
    float hn = (1.f - z) * n + z * hprev;
    h_out[(size_t)uo * Bq + bb] = hn;
    ys_out[(size_t)uo * Bq + bb] = hn;
  }
}

// ys_t[s][u][b] -> out[(s*rsS + b*rsB)*U + u]
__global__ __launch_bounds__(256) void transpose_kernel(
    const float* __restrict__ ys_t, float* __restrict__ out, int rsS, int rsB) {
  int s = blockIdx.x;
  int u0 = blockIdx.y * 32;
  __shared__ float t[32][33];
  int tid = threadIdx.x;
  int c = tid & 31, r = tid >> 5;
#pragma unroll
  for (int i = 0; i < 32; i += 8)
    t[r + i][c] = ys_t[((size_t)s * Uu + u0 + r + i) * Bq + c];
  __syncthreads();
#pragma unroll
  for (int i = 0; i < 32; i += 8) {
    int bb = r + i;
    out[(size_t)(s * rsS + bb * rsB) * Uu + u0 + c] = t[c][bb];
  }
}

// per-row logsumexp over V=50000
__global__ __launch_bounds__(256) void row_lse_kernel(
    const float* __restrict__ logits, float* __restrict__ lse) {
  int row = blockIdx.x;
  int tid = threadIdx.x;
  const float* x = logits + (size_t)row * Vv;
  float m = -INFINITY, ssum = 0.f;
  for (int i = tid; i < Vv; i += 256) {
    float v = x[i];
    if (v > m) {
      ssum = ssum * expf(m - v) + 1.f;
      m = v;
    } else {
      ssum += expf(v - m);
    }
  }
  __shared__ float ms[256], ss[256];
  ms[tid] = m;
  ss[tid] = ssum;
  __syncthreads();
  for (int off = 128; off; off >>= 1) {
    if (tid < off) {
      float m2 = ms[tid + off], s2 = ss[tid + off];
      float M2 = fmaxf(ms[tid], m2);
      ss[tid] = ss[tid] * expf(ms[tid] - M2) + s2 * expf(m2 - M2);
      ms[tid] = M2;
    }
    __syncthreads();
  }
  if (tid == 0) lse[row] = ms[0] + logf(ss[0]);
}

__global__ __launch_bounds__(256) void sub_lse_kernel(
    float* __restrict__ out, const float* __restrict__ lse) {
  size_t i = (size_t)blockIdx.x * 256 + threadIdx.x;  // float4 index
  size_t row = i / (Vv / 4);
  float4* p = (float4*)out + i;
  float4 v = *p;
  float l = lse[row];
  v.x -= l; v.y -= l; v.z -= l; v.w -= l;
  *p = v;
}

// ---------------------------------------------------------------------------
extern "C" void kernel_launch(void* const* d_in, const int* in_sizes, int n_in,
                              void* d_out, int out_size, void* d_ws, size_t ws_size,
                              hipStream_t stream) {
  (void)in_sizes; (void)n_in; (void)out_size;
  const int* xidx = (const int*)d_in[0];
  const int* eidx = (const int*)d_in[1];
  const float* X = (const float*)d_in[2];
  const float* W_gat = (const float*)d_in[3];
  const float* a_src = (const float*)d_in[4];
  const float* a_dst = (const float*)d_in[5];
  const float* b_gat = (const float*)d_in[6];
  const float* w_ih0 = (const float*)d_in[7];
  const float* w_hh0 = (const float*)d_in[8];
  const float* b_ih0 = (const float*)d_in[9];
  const float* b_hh0 = (const float*)d_in[10];
  const float* w_ih1 = (const float*)d_in[11];
  const float* w_hh1 = (const float*)d_in[12];
  const float* b_ih1 = (const float*)d_in[13];
  const float* b_hh1 = (const float*)d_in[14];
  const float* W_out = (const float*)d_in[15];
  const float* b_out = (const float*)d_in[16];
  float* out = (float*)d_out;
  float* ws = (float*)d_ws;

  // workspace layout (float offsets)
  float* wa_src = ws;                  // 1200
  float* wa_dst = ws + 1200;           // 1200
  float* xs     = ws + 2400;           // 1024*900
  float* gi     = ws + 924000;         // 1024*3072 (shared by layer0/layer1)
  float* h_a    = ws + 4069728;        // 1024*32
  float* h_b    = ws + 4102496;        // 1024*32
  float* ys_t   = ws + 4135264;        // 32*1024*32
  float* a1     = ws + 5183840;        // 1024*1024
  float* gru    = ws + 6232416;        // 1024*1024
  float* lse    = ws + 7280992;        // 1024
  // bf16 split buffers (need ~239 MB total ws); deterministic fallback if not
  const size_t WS_NEED_F = 59700000;
  bool use_mfma = (ws_size >= WS_NEED_F * sizeof(float));
  __bf16* whi = (__bf16*)(ws + 7300000);   // 50000*1024 bf16
  __bf16* wlo = (__bf16*)(ws + 32900000);  // 50000*1024 bf16
  __bf16* ghi = (__bf16*)(ws + 58500000);  // 1024*1024 bf16
  __bf16* glo = (__bf16*)(ws + 59100000);  // 1024*1024 bf16

  compute_wa_kernel<<<10, 256, 0, stream>>>(W_gat, a_src, a_dst, wa_src, wa_dst);
  gat_kernel<<<Gq, 256, 0, stream>>>(xidx, eidx, X, W_gat, b_gat, wa_src, wa_dst, xs);

  // gi0 = xs @ w_ih0^T + b_ih0  [1024,3072], rows = s*B+b
  gemm_bias_kernel<64, 64, 1, 1><<<dim3(3072 / 64, 1024 / 64), 256, 0, stream>>>(
      xs, w_ih0, b_ih0, gi, 1024, 3072, DINq);

  hipMemsetAsync(h_a, 0, (size_t)Uu * Bq * sizeof(float), stream);
  {
    float* hin = h_a; float* hout = h_b;
    for (int s = 0; s < Sq; ++s) {
      gru_step_kernel<<<512, 256, 0, stream>>>(
          gi + (size_t)s * Bq * 3 * Uu, w_hh0, b_hh0, hin, hout,
          ys_t + (size_t)s * Uu * Bq);
      float* t = hin; hin = hout; hout = t;
    }
  }
  transpose_kernel<<<dim3(Sq, Uu / 32), 256, 0, stream>>>(ys_t, a1, Bq, 1);

  // gi1 = ys0 @ w_ih1^T + b_ih1
  gemm_bias_kernel<64, 64, 1, 1><<<dim3(3072 / 64, 1024 / 64), 256, 0, stream>>>(
      a1, w_ih1, b_ih1, gi, 1024, 3072, Uu);

  hipMemsetAsync(h_a, 0, (size_t)Uu * Bq * sizeof(float), stream);
  {
    float* hin = h_a; float* hout = h_b;
    for (int s = 0; s < Sq; ++s) {
      gru_step_kernel<<<512, 256, 0, stream>>>(
          gi + (size_t)s * Bq * 3 * Uu, w_hh1, b_hh1, hin, hout,
          ys_t + (size_t)s * Uu * Bq);
      float* t = hin; hin = hout; hout = t;
    }
  }
  // ys1 [S][U][B] -> gru rows b*S+s
  transpose_kernel<<<dim3(Sq, Uu / 32), 256, 0, stream>>>(ys_t, gru, 1, Sq);

  if (use_mfma) {
    split_bf16_kernel<<<2048, 256, 0, stream>>>(W_out, whi, wlo, Vv * Uu / 4);
    split_bf16_kernel<<<1024, 256, 0, stream>>>(gru, ghi, glo, 1024 * Uu / 4);
    logits_mfma_kernel<<<dim3(8, 391), 256, 0, stream>>>(ghi, glo, whi, wlo, b_out, out);
  } else {
    gemm_bias_kernel<128, 128, 2, 2><<<dim3((Vv + 127) / 128, 1024 / 128), 256, 0, stream>>>(
        gru, W_out, b_out, out, 1024, Vv, Uu);
  }

  row_lse_kernel<<<1024, 256, 0, stream>>>(out, lse);
  sub_lse_kernel<<<(1024 * Vv / 4) / 256, 256, 0, stream>>>(out, lse);
}